// Round 18
// baseline (281.252 us; speedup 1.0000x reference)
//
#include <hip/hip_runtime.h>
#include <hip/hip_bf16.h>
#include <cstdint>
#include <cstddef>

// Problem constants
#define B_    8
#define SEQ_  1024
#define C_    768
#define H_    12
#define D_    64
#define TC_   2304          // 3*C
#define M_    8192          // B*SEQ
#define EPS_  1e-7f
#define SCALE_ 0.036084391824351615f  // 768^-0.5

typedef __attribute__((ext_vector_type(8))) short bf16x8;
typedef __attribute__((ext_vector_type(4))) float f32x4;
typedef __attribute__((ext_vector_type(4))) int   i32x4;

// int8 -> bf16 integer levels (exact for |v|<=255)
__device__ __forceinline__ void expand16(int4 raw, int4& lo, int4& hi) {
  union { int4 v; signed char c[16]; } u; u.v = raw;
  unsigned short s[16];
  #pragma unroll
  for (int j = 0; j < 16; ++j) {
    float f = (float)(int)u.c[j];
    s[j] = (unsigned short)(__float_as_uint(f) >> 16);
  }
  lo = *(const int4*)&s[0]; hi = *(const int4*)&s[8];
}

__device__ __forceinline__ int8_t quant1(float v, float s) {
  float y = fminf(fabsf(v) / s, 1.0f);
  int q = (int)rintf(y * 127.0f);       // half-to-even, matches jnp.round
  return (int8_t)(v < 0.f ? -q : q);
}
__device__ __forceinline__ int4 qpack16(float4 a, float4 b, float4 c, float4 d, float s) {
  union { int4 v; int8_t q[16]; } pk;
  pk.q[0]=quant1(a.x,s);  pk.q[1]=quant1(a.y,s);  pk.q[2]=quant1(a.z,s);  pk.q[3]=quant1(a.w,s);
  pk.q[4]=quant1(b.x,s);  pk.q[5]=quant1(b.y,s);  pk.q[6]=quant1(b.z,s);  pk.q[7]=quant1(b.w,s);
  pk.q[8]=quant1(c.x,s);  pk.q[9]=quant1(c.y,s);  pk.q[10]=quant1(c.z,s); pk.q[11]=quant1(c.w,s);
  pk.q[12]=quant1(d.x,s); pk.q[13]=quant1(d.y,s); pk.q[14]=quant1(d.z,s); pk.q[15]=quant1(d.w,s);
  return pk.v;
}

// ---------------- init global stats ----------------
// g[0]=max|x| g[1]=max|qkv_w| g[2]=max|proj_w| g[3]=max|q| g[4]=max|k| g[5]=max|v|
// g[6]=min softmax-denom  g[7]=max|attn_out|
__global__ void k_init(float* g) {
  if (threadIdx.x == 0) {
    g[0]=0.f; g[1]=0.f; g[2]=0.f; g[3]=0.f; g[4]=0.f; g[5]=0.f;
    g[6]=3.402823466e+38f;
    g[7]=0.f;
  }
}

// ---------------- fused abs-max over x / qkv_w / proj_w, 1 atomic per block ----------------
__global__ __launch_bounds__(256) void k_absmax_fused(const float4* __restrict__ x,
                                                      const float4* __restrict__ w1,
                                                      const float4* __restrict__ w2,
                                                      float* g) {
  __shared__ float red[4];
  const int blk = blockIdx.x;
  const float4* p; unsigned n4; float* gout; int b0, nb;
  if (blk < 384)      { p = x;  n4 = 1572864u; gout = &g[0]; b0 = 0;   nb = 384; }
  else if (blk < 480) { p = w1; n4 = 442368u;  gout = &g[1]; b0 = 384; nb = 96;  }
  else                { p = w2; n4 = 147456u;  gout = &g[2]; b0 = 480; nb = 48;  }
  float m = 0.f;
  for (unsigned i = (unsigned)(blk - b0) * 256u + threadIdx.x; i < n4; i += (unsigned)nb * 256u) {
    float4 v = p[i];
    m = fmaxf(m, fmaxf(fmaxf(fabsf(v.x), fabsf(v.y)), fmaxf(fabsf(v.z), fabsf(v.w))));
  }
  #pragma unroll
  for (int off = 32; off; off >>= 1) m = fmaxf(m, __shfl_xor(m, off));
  if ((threadIdx.x & 63) == 0) red[threadIdx.x >> 6] = m;
  __syncthreads();
  if (threadIdx.x == 0) {
    m = fmaxf(fmaxf(red[0], red[1]), fmaxf(red[2], red[3]));
    atomicMax((unsigned int*)gout, __float_as_uint(m));
  }
}

// ---------------- signed fake-quant -> int8 levels, float4-vectorized (weights only) --------
__device__ __forceinline__ void quant_seg4(const float4* __restrict__ in, unsigned n4, float s,
                                           int8_t* __restrict__ out, unsigned i0, unsigned stride) {
  for (unsigned i = i0; i < n4; i += stride) {
    float4 v = in[i];
    union { unsigned int u; int8_t c[4]; } pk;
    pk.c[0] = quant1(v.x, s);
    pk.c[1] = quant1(v.y, s);
    pk.c[2] = quant1(v.z, s);
    pk.c[3] = quant1(v.w, s);
    *(unsigned int*)&out[(size_t)i * 4] = pk.u;
  }
}
__global__ __launch_bounds__(256) void k_quant_fused(const float4* __restrict__ w1,
                                                     const float4* __restrict__ w2,
                                                     const float* __restrict__ g,
                                                     int8_t* __restrict__ wq,
                                                     int8_t* __restrict__ pw) {
  const int blk = blockIdx.x;
  if (blk < 432) quant_seg4(w1, 442368u, g[1] + EPS_, wq, (unsigned)blk * 256u + threadIdx.x, 432u * 256u);
  else           quant_seg4(w2, 147456u, g[2] + EPS_, pw, (unsigned)(blk - 432) * 256u + threadIdx.x, 144u * 256u);
}

// ---------------- fused-quant-A i8 GEMM: C = alpha*(quant(Af).Bt^T) + bias ----------------
// A is f32; staging quantizes on the fly (bit-identical to the standalone quant kernel) --
// the GEMM K-loop is latency-bound with idle VALU, so the quant work is free and two whole
// memory-bound passes (x-quant, attn-out-quant) are deleted. B int8 with depth-1 reg
// prefetch; A f32 loads issued before the barrier so the barrier wait covers them.
__global__ __launch_bounds__(256) void k_gemm8i_qa(const float* __restrict__ Af,
                                                   const int8_t* __restrict__ Bt,
                                                   const float* __restrict__ bias,
                                                   float* __restrict__ C,
                                                   int Mn, int Nn, int Kn,
                                                   const float* __restrict__ sA, const float* __restrict__ sB,
                                                   float* pmax, int partDiv) {
  __shared__ int8_t As[4][128][16];   // [k-slot][row][16B]
  __shared__ int8_t Bs[4][128][16];
  const int tid = threadIdx.x;
  // bijective XCD swizzle (nwg % 8 == 0 for both GEMMs)
  int flat = blockIdx.y * gridDim.x + blockIdx.x;
  int chunk = (gridDim.x * gridDim.y) >> 3;
  int nf = (flat & 7) * chunk + (flat >> 3);
  const int n0 = (nf % gridDim.x) * 128, m0 = (nf / gridDim.x) * 128;
  const int wid = tid >> 6, lane = tid & 63;
  const int wr = wid >> 1, wc = wid & 1;            // 2x2 waves -> 64x64 each
  const int lrow = lane & 15;
  const int lslot = lane >> 4;                      // k slot 0..3 (16 bytes each)
  i32x4 acc[4][4] = {};
  const int srow = tid & 127;
  const int slot0 = tid >> 7;                       // 0 or 1
  const float sq = sA[0] + EPS_;
  const float*  gaf = Af + (size_t)(m0 + srow) * Kn + slot0 * 16;
  const int8_t* gb  = Bt + (size_t)(n0 + srow) * Kn + slot0 * 16;
  const int nt = Kn >> 6;
  int4 rb0 = *(const int4*)(gb);
  int4 rb1 = *(const int4*)(gb + 32);
  for (int t = 0; t < nt; ++t) {
    // issue A f32 loads for this tile before the barrier (register loads; barrier covers them)
    const float4* pa = (const float4*)(gaf + (size_t)t * 64);
    float4 x0 = pa[0], x1 = pa[1], x2 = pa[2],  x3 = pa[3];    // slot0
    float4 y0 = pa[8], y1 = pa[9], y2 = pa[10], y3 = pa[11];   // slot0+2 (+32 floats)
    if (t) __syncthreads();           // all waves done reading LDS from prev step
    *(int4*)&As[slot0][srow][0]     = qpack16(x0, x1, x2, x3, sq);
    *(int4*)&As[slot0 + 2][srow][0] = qpack16(y0, y1, y2, y3, sq);
    *(int4*)&Bs[slot0][srow][0]     = rb0;
    *(int4*)&Bs[slot0 + 2][srow][0] = rb1;
    if (t + 1 < nt) {
      const int ko = (t + 1) << 6;
      rb0 = *(const int4*)(gb + ko);
      rb1 = *(const int4*)(gb + ko + 32);
    }
    __syncthreads();                  // LDS tile ready
    i32x4 af[4], bfr[4];
    #pragma unroll
    for (int i = 0; i < 4; ++i) af[i]  = *(const i32x4*)&As[lslot][wr * 64 + i * 16 + lrow][0];
    #pragma unroll
    for (int j = 0; j < 4; ++j) bfr[j] = *(const i32x4*)&Bs[lslot][wc * 64 + j * 16 + lrow][0];
    #pragma unroll
    for (int i = 0; i < 4; ++i)
      #pragma unroll
      for (int j = 0; j < 4; ++j)
        acc[i][j] = __builtin_amdgcn_mfma_i32_16x16x64_i8(af[i], bfr[j], acc[i][j], 0, 0, 0);
  }
  const float alpha = (sA[0] + EPS_) * (sB[0] + EPS_) * (1.0f / 16129.0f);
  const int orow = (lane >> 4) << 2;
  float amax = 0.f;
  #pragma unroll
  for (int i = 0; i < 4; ++i) {
    #pragma unroll
    for (int j = 0; j < 4; ++j) {
      int col = n0 + wc * 64 + j * 16 + lrow;
      float bc = bias[col];
      #pragma unroll
      for (int rr = 0; rr < 4; ++rr) {
        int row = m0 + wr * 64 + i * 16 + orow + rr;
        float val = (float)acc[i][j][rr] * alpha + bc;
        C[(size_t)row * Nn + col] = val;
        amax = fmaxf(amax, fabsf(val));
      }
    }
  }
  if (pmax) {
    #pragma unroll
    for (int off = 32; off; off >>= 1) amax = fmaxf(amax, __shfl_xor(amax, off));
    if (lane == 0) atomicMax((unsigned int*)&pmax[n0 / partDiv], __float_as_uint(amax));
  }
}

// ---------------- quantize qkv into int8 head-layouts (tiled, coalesced vT) ----------------
__global__ __launch_bounds__(256) void k_quant_heads(const float* __restrict__ qkvf, const float* __restrict__ g,
                                                     int8_t* __restrict__ qo, int8_t* __restrict__ ko,
                                                     int8_t* __restrict__ vT) {
  __shared__ float vt[64][65];
  const int bh = blockIdx.x >> 4, nt = blockIdx.x & 15;
  const int b = bh / 12, h = bh % 12;
  const int n0 = nt * 64;
  const int tid = threadIdx.x;
  const float s0 = g[3] + EPS_, s1 = g[4] + EPS_, s2 = g[5] + EPS_;
  const int r = tid >> 2, dc = tid & 3;             // row in tile, 16-elem d chunk
  const size_t mrow = (size_t)(b * 1024 + n0 + r) * 2304;
  // q part
  {
    const float4* src = (const float4*)(qkvf + mrow + h * 64 + dc * 16);
    *(int4*)&qo[((size_t)bh * 1024 + n0 + r) * 64 + dc * 16] =
        qpack16(src[0], src[1], src[2], src[3], s0);
  }
  // k part
  {
    const float4* src = (const float4*)(qkvf + mrow + 768 + h * 64 + dc * 16);
    *(int4*)&ko[((size_t)bh * 1024 + n0 + r) * 64 + dc * 16] =
        qpack16(src[0], src[1], src[2], src[3], s1);
  }
  // v part: stash transposed in LDS (f32), quantize+pack on the way out
  {
    const float4* src = (const float4*)(qkvf + mrow + 1536 + h * 64 + dc * 16);
    float4 v0 = src[0], v1 = src[1], v2 = src[2], v3 = src[3];
    vt[dc*16+ 0][r]=v0.x; vt[dc*16+ 1][r]=v0.y; vt[dc*16+ 2][r]=v0.z; vt[dc*16+ 3][r]=v0.w;
    vt[dc*16+ 4][r]=v1.x; vt[dc*16+ 5][r]=v1.y; vt[dc*16+ 6][r]=v1.z; vt[dc*16+ 7][r]=v1.w;
    vt[dc*16+ 8][r]=v2.x; vt[dc*16+ 9][r]=v2.y; vt[dc*16+10][r]=v2.z; vt[dc*16+11][r]=v2.w;
    vt[dc*16+12][r]=v3.x; vt[dc*16+13][r]=v3.y; vt[dc*16+14][r]=v3.z; vt[dc*16+15][r]=v3.w;
  }
  __syncthreads();
  {
    const int d = tid >> 2, nc = tid & 3;
    union { int4 v; int8_t c[16]; } pk;
    #pragma unroll
    for (int e = 0; e < 16; ++e) pk.c[e] = quant1(vt[d][nc * 16 + e], s2);
    *(int4*)&vT[((size_t)bh * 64 + d) * 1024 + n0 + nc * 16] = pk.v;
  }
}

// ---------------- attention pass 1 (native-i8 swapped QK^T, 64-row blocks, prefetch) --------
__global__ __launch_bounds__(256) void k_attn_stats_mfma(
    const int8_t* __restrict__ qi8, const int8_t* __restrict__ ki8,
    const float* __restrict__ g, float* __restrict__ rowmax, float* __restrict__ denomv,
    unsigned int* __restrict__ gminden) {
  __shared__ int8_t Ks[4][64][16];
  __shared__ float red[4];
  const int bh = blockIdx.x >> 4, rt = blockIdx.x & 15;
  const int tid = threadIdx.x, w = tid >> 6, lane = tid & 63;
  const int lrow = lane & 15, lslot = lane >> 4;
  const int8_t* qbase = qi8 + (size_t)bh * 65536;
  const int8_t* kbase = ki8 + (size_t)bh * 65536;
  const i32x4 qf = *(const i32x4*)(qbase + (size_t)(rt*64 + w*16 + lrow) * 64 + lslot * 16);
  const float qkScale = (g[3] + EPS_) * (g[4] + EPS_) * (1.0f / 16129.0f) * SCALE_;
  float m = -3.0e38f, den = 0.f;
  const int krow = tid & 63, kslot = tid >> 6;      // staging: 16B per thread
  int4 kraw = *(const int4*)(kbase + (size_t)krow * 64 + kslot * 16);
  for (int t = 0; t < 16; ++t) {
    __syncthreads();
    *(int4*)&Ks[kslot][krow][0] = kraw;
    if (t < 15)
      kraw = *(const int4*)(kbase + (size_t)(t + 1) * 4096 + (size_t)krow * 64 + kslot * 16);
    __syncthreads();
    i32x4 acc[4] = {};
    #pragma unroll
    for (int j = 0; j < 4; ++j) {
      i32x4 kf = *(const i32x4*)&Ks[lslot][j * 16 + lrow][0];
      acc[j] = __builtin_amdgcn_mfma_i32_16x16x64_i8(kf, qf, acc[j], 0, 0, 0);
    }
    float mnew = m;
    #pragma unroll
    for (int j = 0; j < 4; ++j)
      #pragma unroll
      for (int rr = 0; rr < 4; ++rr)
        mnew = fmaxf(mnew, (float)acc[j][rr] * qkScale);
    float d = den * __expf(m - mnew);
    #pragma unroll
    for (int j = 0; j < 4; ++j)
      #pragma unroll
      for (int rr = 0; rr < 4; ++rr)
        d += __expf((float)acc[j][rr] * qkScale - mnew);
    den = d; m = mnew;
  }
  // merge the 4 hi-lane k-partitions
  #pragma unroll
  for (int off = 16; off <= 32; off <<= 1) {
    float mo = __shfl_xor(m, off);
    float doo = __shfl_xor(den, off);
    float mg = fmaxf(m, mo);
    den = den * __expf(m - mg) + doo * __expf(mo - mg);
    m = mg;
  }
  if (lane < 16) {
    size_t rg = (size_t)bh * 1024 + rt * 64 + w * 16 + lane;
    rowmax[rg] = m;
    denomv[rg] = den;
  }
  // one atomic per block
  float bm = den;
  #pragma unroll
  for (int off = 1; off < 16; off <<= 1) bm = fminf(bm, __shfl_xor(bm, off));
  if (lane == 0) red[w] = bm;
  __syncthreads();
  if (tid == 0)
    atomicMin(gminden, __float_as_uint(fminf(fminf(red[0], red[1]), fminf(red[2], red[3]))));
}

// ---------------- attention pass 2 (i8 QK^T + bf16 PV, 64-row blocks, prefetch) -------------
__global__ __launch_bounds__(256) void k_attn_pv_mfma(
    const int8_t* __restrict__ qi8, const int8_t* __restrict__ ki8, const int8_t* __restrict__ vti8,
    const float* __restrict__ g, const unsigned int* __restrict__ gminden,
    const float* __restrict__ rowmax, const float* __restrict__ denomv,
    float* __restrict__ aof, float* __restrict__ gamax) {
  __shared__ int8_t Ks[4][64][16];
  __shared__ unsigned short Vs[64 * 64];
  __shared__ unsigned short Ps[64 * 64];
  __shared__ float red[4];
  const int bh = blockIdx.x >> 4, rt = blockIdx.x & 15;
  const int b = bh / 12, h = bh % 12;
  const int tid = threadIdx.x, w = tid >> 6, lane = tid & 63;
  const int lrow = lane & 15, lslot = lane >> 4, lko = lslot << 3;
  const int8_t* qbase = qi8 + (size_t)bh * 65536;
  const int8_t* kbase = ki8 + (size_t)bh * 65536;
  const int8_t* vbase = vti8 + (size_t)bh * 65536;
  const i32x4 qf = *(const i32x4*)(qbase + (size_t)(rt*64 + w*16 + lrow) * 64 + lslot * 16);
  const float qkScale = (g[3] + EPS_) * (g[4] + EPS_) * (1.0f / 16129.0f) * SCALE_;
  const float minden = __uint_as_float(*gminden);
  const float sa = 1.0f / minden + EPS_;
  const float invSa = 1.0f / sa;
  const float sv = g[5] + EPS_;
  const float pvScale = sa * sv * (1.0f / 32385.0f);   // /(255*127)
  const float rm  = rowmax[(size_t)bh * 1024 + rt * 64 + w * 16 + lrow];
  const float ivd = 1.0f / denomv[(size_t)bh * 1024 + rt * 64 + w * 16 + lrow];
  f32x4 accO[4] = {};
  const int krow = tid & 63, kslot = tid >> 6;      // K staging: raw int8, 16B/thread
  const int srow = tid >> 2, sc = tid & 3;          // V staging: expand to bf16, swizzled
  const int sx = (srow & 7) << 4;
  int4 kraw = *(const int4*)(kbase + (size_t)krow * 64 + kslot * 16);
  int4 vraw = *(const int4*)(vbase + (size_t)srow * 1024 + sc * 16);
  for (int t = 0; t < 16; ++t) {
    __syncthreads();
    *(int4*)&Ks[kslot][krow][0] = kraw;
    {
      int4 lo, hi;
      int bb = srow * 128 + sc * 32;
      expand16(vraw, lo, hi);
      *(int4*)((char*)Vs + ( bb       ^ sx)) = lo;
      *(int4*)((char*)Vs + ((bb + 16) ^ sx)) = hi;
    }
    if (t < 15) {
      kraw = *(const int4*)(kbase + (size_t)(t + 1) * 4096 + (size_t)krow * 64 + kslot * 16);
      vraw = *(const int4*)(vbase + (size_t)srow * 1024 + (t + 1) * 64 + sc * 16);
    }
    __syncthreads();
    i32x4 acc[4] = {};
    #pragma unroll
    for (int j = 0; j < 4; ++j) {
      i32x4 kf = *(const i32x4*)&Ks[lslot][j * 16 + lrow][0];
      acc[j] = __builtin_amdgcn_mfma_i32_16x16x64_i8(kf, qf, acc[j], 0, 0, 0);
    }
    // softmax -> unsigned 8-bit levels (exact bf16) -> Ps (in-lane)
    const int q = w * 16 + lrow;
    const int kb = lslot << 2;
    #pragma unroll
    for (int j = 0; j < 4; ++j) {
      float a0 = rintf(fminf(__expf((float)acc[j][0] * qkScale - rm) * ivd * invSa, 1.0f) * 255.0f);
      float a1 = rintf(fminf(__expf((float)acc[j][1] * qkScale - rm) * ivd * invSa, 1.0f) * 255.0f);
      float a2 = rintf(fminf(__expf((float)acc[j][2] * qkScale - rm) * ivd * invSa, 1.0f) * 255.0f);
      float a3 = rintf(fminf(__expf((float)acc[j][3] * qkScale - rm) * ivd * invSa, 1.0f) * 255.0f);
      uint2 pk;
      pk.x = (__float_as_uint(a0) >> 16) | ((__float_as_uint(a1) >> 16) << 16);
      pk.y = (__float_as_uint(a2) >> 16) | ((__float_as_uint(a3) >> 16) << 16);
      int byteoff = (q * 128 + (j * 16 + kb) * 2) ^ ((q & 7) << 4);
      *(uint2*)((char*)Ps + byteoff) = pk;
    }
    // O += P @ V  (bf16 MFMA; P in 0..255 exact bf16)
    #pragma unroll
    for (int ks = 0; ks < 2; ++ks) {
      bf16x8 pf = *(const bf16x8*)((const char*)Ps + ((q * 128 + (ks*32 + lko) * 2) ^ ((q & 7) << 4)));
      #pragma unroll
      for (int j = 0; j < 4; ++j) {
        int row = j * 16 + lrow;
        bf16x8 vf = *(const bf16x8*)((const char*)Vs + ((row * 128 + (ks*32 + lko) * 2) ^ ((row & 7) << 4)));
        accO[j] = __builtin_amdgcn_mfma_f32_16x16x32_bf16(pf, vf, accO[j], 0, 0, 0);
      }
    }
  }
  float amax = 0.f;
  #pragma unroll
  for (int j = 0; j < 4; ++j) {
    int d = j * 16 + lrow;
    #pragma unroll
    for (int rr = 0; rr < 4; ++rr) {
      int row = rt * 64 + w * 16 + (lane >> 4) * 4 + rr;
      float val = accO[j][rr] * pvScale;
      aof[((size_t)(b * 1024 + row)) * 768 + h * 64 + d] = val;
      amax = fmaxf(amax, fabsf(val));
    }
  }
  #pragma unroll
  for (int off = 1; off < 64; off <<= 1) amax = fmaxf(amax, __shfl_xor(amax, off));
  if (lane == 0) red[w] = amax;
  __syncthreads();
  if (tid == 0)
    atomicMax((unsigned int*)gamax, __float_as_uint(fmaxf(fmaxf(red[0], red[1]), fmaxf(red[2], red[3]))));
}

extern "C" void kernel_launch(void* const* d_in, const int* in_sizes, int n_in,
                              void* d_out, int out_size, void* d_ws, size_t ws_size,
                              hipStream_t stream) {
  const float* x      = (const float*)d_in[0];   // [8,1024,768]
  const float* qkv_w  = (const float*)d_in[1];   // [2304,768]
  const float* qkv_b  = (const float*)d_in[2];   // [2304]
  const float* proj_w = (const float*)d_in[3];   // [768,768]
  const float* proj_b = (const float*)d_in[4];   // [768]
  float* out = (float*)d_out;

  char* w = (char*)d_ws;
  float*          g      = (float*)(w + 0);                 // 8 stats
  float*          rowmax = (float*)(w + 256);               // 393216 B
  float*          denomv = (float*)(w + 393472);            // 393216 B
  int8_t*         qi8    = (int8_t*)(w + 786688);           // 6291456 B
  int8_t*         ki8    = (int8_t*)(w + 7078144);          // 6291456 B
  int8_t*         vT     = (int8_t*)(w + 13369600);         // 6291456 B
  int8_t*         pw8    = (int8_t*)(w + 19661056);         //  589824 B
  int8_t*         wq8    = (int8_t*)(w + 33423616);         // 1769472 B
  float*          qkvf   = (float*)(w + 36962560);          // 75497472 B f32 (dead after quant_heads)
  float*          aof    = (float*)(w + 36962560);          // 25165824 B (aliases dead qkvf)

  hipLaunchKernelGGL(k_init, dim3(1), dim3(64), 0, stream, g);

  hipLaunchKernelGGL(k_absmax_fused, dim3(528), dim3(256), 0, stream,
                     (const float4*)x, (const float4*)qkv_w, (const float4*)proj_w, g);

  hipLaunchKernelGGL(k_quant_fused, dim3(576), dim3(256), 0, stream,
                     (const float4*)qkv_w, (const float4*)proj_w, g, wq8, pw8);

  // qkv = quant(x) @ wq^T * (sx*sw/127^2) + b -> f32 [8192][2304]; per-part |max| -> g[3..5]
  hipLaunchKernelGGL(k_gemm8i_qa, dim3(TC_ / 128, M_ / 128), dim3(256), 0, stream,
                     x, wq8, qkv_b, qkvf, M_, TC_, C_, &g[0], &g[1], &g[3], 768);

  hipLaunchKernelGGL(k_quant_heads, dim3(1536), dim3(256), 0, stream, qkvf, g, qi8, ki8, vT);

  hipLaunchKernelGGL(k_attn_stats_mfma, dim3(1536), dim3(256), 0, stream,
                     qi8, ki8, g, rowmax, denomv, (unsigned int*)&g[6]);
  hipLaunchKernelGGL(k_attn_pv_mfma, dim3(1536), dim3(256), 0, stream,
                     qi8, ki8, vT, g, (const unsigned int*)&g[6], rowmax, denomv, aof, &g[7]);

  // out = quant(aof) @ pw8^T * (sao*spw/127^2) + proj_b -> d_out f32 [8192][768]
  hipLaunchKernelGGL(k_gemm8i_qa, dim3(C_ / 128, M_ / 128), dim3(256), 0, stream,
                     aof, pw8, proj_b, out, M_, C_, C_, &g[7], &g[2], (float*)nullptr, 1);

  (void)in_sizes; (void)n_in; (void)out_size; (void)ws_size;
}

// Round 19
// 224.598 us; speedup vs baseline: 1.2522x; 1.2522x over previous
//
#include <hip/hip_runtime.h>
#include <hip/hip_bf16.h>
#include <cstdint>
#include <cstddef>

// Problem constants
#define B_    8
#define SEQ_  1024
#define C_    768
#define H_    12
#define D_    64
#define TC_   2304          // 3*C
#define M_    8192          // B*SEQ
#define EPS_  1e-7f
#define SCALE_ 0.036084391824351615f  // 768^-0.5

typedef __attribute__((ext_vector_type(8))) short bf16x8;
typedef __attribute__((ext_vector_type(4))) float f32x4;
typedef __attribute__((ext_vector_type(4))) int   i32x4;

// int8 -> bf16 integer levels (exact for |v|<=255)
__device__ __forceinline__ void expand16(int4 raw, int4& lo, int4& hi) {
  union { int4 v; signed char c[16]; } u; u.v = raw;
  unsigned short s[16];
  #pragma unroll
  for (int j = 0; j < 16; ++j) {
    float f = (float)(int)u.c[j];
    s[j] = (unsigned short)(__float_as_uint(f) >> 16);
  }
  lo = *(const int4*)&s[0]; hi = *(const int4*)&s[8];
}

__device__ __forceinline__ int8_t quant1(float v, float s) {
  float y = fminf(fabsf(v) / s, 1.0f);
  int q = (int)rintf(y * 127.0f);       // half-to-even, matches jnp.round
  return (int8_t)(v < 0.f ? -q : q);
}
__device__ __forceinline__ int4 qpack16(float4 a, float4 b, float4 c, float4 d, float s) {
  union { int4 v; int8_t q[16]; } pk;
  pk.q[0]=quant1(a.x,s);  pk.q[1]=quant1(a.y,s);  pk.q[2]=quant1(a.z,s);  pk.q[3]=quant1(a.w,s);
  pk.q[4]=quant1(b.x,s);  pk.q[5]=quant1(b.y,s);  pk.q[6]=quant1(b.z,s);  pk.q[7]=quant1(b.w,s);
  pk.q[8]=quant1(c.x,s);  pk.q[9]=quant1(c.y,s);  pk.q[10]=quant1(c.z,s); pk.q[11]=quant1(c.w,s);
  pk.q[12]=quant1(d.x,s); pk.q[13]=quant1(d.y,s); pk.q[14]=quant1(d.z,s); pk.q[15]=quant1(d.w,s);
  return pk.v;
}

// ---------------- init global stats ----------------
// g[0]=max|x| g[1]=max|qkv_w| g[2]=max|proj_w| g[3]=max|q| g[4]=max|k| g[5]=max|v|
// g[6]=min softmax-denom  g[7]=max|attn_out|
__global__ void k_init(float* g) {
  if (threadIdx.x == 0) {
    g[0]=0.f; g[1]=0.f; g[2]=0.f; g[3]=0.f; g[4]=0.f; g[5]=0.f;
    g[6]=3.402823466e+38f;
    g[7]=0.f;
  }
}

// ---------------- fused abs-max over x / qkv_w / proj_w, 1 atomic per block ----------------
__global__ __launch_bounds__(256) void k_absmax_fused(const float4* __restrict__ x,
                                                      const float4* __restrict__ w1,
                                                      const float4* __restrict__ w2,
                                                      float* g) {
  __shared__ float red[4];
  const int blk = blockIdx.x;
  const float4* p; unsigned n4; float* gout; int b0, nb;
  if (blk < 384)      { p = x;  n4 = 1572864u; gout = &g[0]; b0 = 0;   nb = 384; }
  else if (blk < 480) { p = w1; n4 = 442368u;  gout = &g[1]; b0 = 384; nb = 96;  }
  else                { p = w2; n4 = 147456u;  gout = &g[2]; b0 = 480; nb = 48;  }
  float m = 0.f;
  for (unsigned i = (unsigned)(blk - b0) * 256u + threadIdx.x; i < n4; i += (unsigned)nb * 256u) {
    float4 v = p[i];
    m = fmaxf(m, fmaxf(fmaxf(fabsf(v.x), fabsf(v.y)), fmaxf(fabsf(v.z), fabsf(v.w))));
  }
  #pragma unroll
  for (int off = 32; off; off >>= 1) m = fmaxf(m, __shfl_xor(m, off));
  if ((threadIdx.x & 63) == 0) red[threadIdx.x >> 6] = m;
  __syncthreads();
  if (threadIdx.x == 0) {
    m = fmaxf(fmaxf(red[0], red[1]), fmaxf(red[2], red[3]));
    atomicMax((unsigned int*)gout, __float_as_uint(m));
  }
}

// ---------------- signed fake-quant -> int8 levels, float4-vectorized (G13) ----------------
__device__ __forceinline__ void quant_seg4(const float4* __restrict__ in, unsigned n4, float s,
                                           int8_t* __restrict__ out, unsigned i0, unsigned stride) {
  for (unsigned i = i0; i < n4; i += stride) {
    float4 v = in[i];
    union { unsigned int u; int8_t c[4]; } pk;
    pk.c[0] = quant1(v.x, s);
    pk.c[1] = quant1(v.y, s);
    pk.c[2] = quant1(v.z, s);
    pk.c[3] = quant1(v.w, s);
    *(unsigned int*)&out[(size_t)i * 4] = pk.u;
  }
}
__global__ __launch_bounds__(256) void k_quant_fused(const float4* __restrict__ x,
                                                     const float4* __restrict__ w1,
                                                     const float4* __restrict__ w2,
                                                     const float* __restrict__ g,
                                                     int8_t* __restrict__ xq,
                                                     int8_t* __restrict__ wq,
                                                     int8_t* __restrict__ pw) {
  const int blk = blockIdx.x;
  if (blk < 1536)      quant_seg4(x,  1572864u, g[0] + EPS_, xq, (unsigned)blk * 256u + threadIdx.x, 1536u * 256u);
  else if (blk < 1968) quant_seg4(w1, 442368u,  g[1] + EPS_, wq, (unsigned)(blk - 1536) * 256u + threadIdx.x, 432u * 256u);
  else                 quant_seg4(w2, 147456u,  g[2] + EPS_, pw, (unsigned)(blk - 1968) * 256u + threadIdx.x, 144u * 256u);
}

__global__ __launch_bounds__(256) void k_quant_i8(const float4* __restrict__ in, unsigned n4,
                                                  const float* __restrict__ gmax,
                                                  int8_t* __restrict__ out) {
  const float s = *gmax + EPS_;
  quant_seg4(in, n4, s, out, blockIdx.x * blockDim.x + threadIdx.x, gridDim.x * blockDim.x);
}

// ---------------- native-i8 MFMA GEMM, 128x128, depth-2 reg prefetch (round-14 proven) -----
__global__ __launch_bounds__(256) void k_gemm8i(const int8_t* __restrict__ A,
                                                const int8_t* __restrict__ Bt,
                                                const float* __restrict__ bias,
                                                float* __restrict__ C,
                                                int Mn, int Nn, int Kn,
                                                const float* __restrict__ sA, const float* __restrict__ sB,
                                                float* pmax, int partDiv) {
  __shared__ int8_t As[4][128][16];   // [k-slot][row][16B]
  __shared__ int8_t Bs[4][128][16];
  const int tid = threadIdx.x;
  // bijective XCD swizzle (nwg % 8 == 0 for both GEMMs)
  int flat = blockIdx.y * gridDim.x + blockIdx.x;
  int chunk = (gridDim.x * gridDim.y) >> 3;
  int nf = (flat & 7) * chunk + (flat >> 3);
  const int n0 = (nf % gridDim.x) * 128, m0 = (nf / gridDim.x) * 128;
  const int wid = tid >> 6, lane = tid & 63;
  const int wr = wid >> 1, wc = wid & 1;            // 2x2 waves -> 64x64 each
  const int lrow = lane & 15;
  const int lslot = lane >> 4;                      // k slot 0..3 (16 bytes each)
  i32x4 acc[4][4] = {};
  const int srow = tid & 127;
  const int slot0 = tid >> 7;                       // 0 or 1
  const int8_t* ga = A  + (size_t)(m0 + srow) * Kn + slot0 * 16;
  const int8_t* gb = Bt + (size_t)(n0 + srow) * Kn + slot0 * 16;
  const int nt = Kn >> 6;                           // 12 for both GEMMs (even)
  int4 ra0_0 = *(const int4*)(ga);
  int4 ra1_0 = *(const int4*)(ga + 32);
  int4 rb0_0 = *(const int4*)(gb);
  int4 rb1_0 = *(const int4*)(gb + 32);
  int4 ra0_1 = *(const int4*)(ga + 64);
  int4 ra1_1 = *(const int4*)(ga + 96);
  int4 rb0_1 = *(const int4*)(gb + 64);
  int4 rb1_1 = *(const int4*)(gb + 96);
  #define KSTEP(SET, T)                                                        \
    if (T) __syncthreads();                                                    \
    *(int4*)&As[slot0][srow][0]     = ra0_##SET;                               \
    *(int4*)&As[slot0 + 2][srow][0] = ra1_##SET;                               \
    *(int4*)&Bs[slot0][srow][0]     = rb0_##SET;                               \
    *(int4*)&Bs[slot0 + 2][srow][0] = rb1_##SET;                               \
    if ((T) + 2 < nt) {                                                        \
      const int ko_ = ((T) + 2) << 6;                                          \
      ra0_##SET = *(const int4*)(ga + ko_);                                    \
      ra1_##SET = *(const int4*)(ga + ko_ + 32);                               \
      rb0_##SET = *(const int4*)(gb + ko_);                                    \
      rb1_##SET = *(const int4*)(gb + ko_ + 32);                               \
    }                                                                          \
    __syncthreads();                                                           \
    {                                                                          \
      i32x4 af[4], bfr[4];                                                     \
      _Pragma("unroll")                                                        \
      for (int i = 0; i < 4; ++i) af[i]  = *(const i32x4*)&As[lslot][wr * 64 + i * 16 + lrow][0]; \
      _Pragma("unroll")                                                        \
      for (int j = 0; j < 4; ++j) bfr[j] = *(const i32x4*)&Bs[lslot][wc * 64 + j * 16 + lrow][0]; \
      _Pragma("unroll")                                                        \
      for (int i = 0; i < 4; ++i)                                              \
        _Pragma("unroll")                                                      \
        for (int j = 0; j < 4; ++j)                                            \
          acc[i][j] = __builtin_amdgcn_mfma_i32_16x16x64_i8(af[i], bfr[j], acc[i][j], 0, 0, 0); \
    }
  for (int t = 0; t < nt; t += 2) {
    KSTEP(0, t)
    KSTEP(1, t + 1)
  }
  #undef KSTEP
  const float alpha = (sA[0] + EPS_) * (sB[0] + EPS_) * (1.0f / 16129.0f);
  const int orow = (lane >> 4) << 2;
  float amax = 0.f;
  #pragma unroll
  for (int i = 0; i < 4; ++i) {
    #pragma unroll
    for (int j = 0; j < 4; ++j) {
      int col = n0 + wc * 64 + j * 16 + lrow;
      float bc = bias[col];
      #pragma unroll
      for (int rr = 0; rr < 4; ++rr) {
        int row = m0 + wr * 64 + i * 16 + orow + rr;
        float val = (float)acc[i][j][rr] * alpha + bc;
        C[(size_t)row * Nn + col] = val;
        amax = fmaxf(amax, fabsf(val));
      }
    }
  }
  if (pmax) {
    #pragma unroll
    for (int off = 32; off; off >>= 1) amax = fmaxf(amax, __shfl_xor(amax, off));
    if (lane == 0) atomicMax((unsigned int*)&pmax[n0 / partDiv], __float_as_uint(amax));
  }
}

// ---------------- quantize qkv into int8 head-layouts (tiled, coalesced vT) ----------------
__global__ __launch_bounds__(256) void k_quant_heads(const float* __restrict__ qkvf, const float* __restrict__ g,
                                                     int8_t* __restrict__ qo, int8_t* __restrict__ ko,
                                                     int8_t* __restrict__ vT) {
  __shared__ float vt[64][65];
  const int bh = blockIdx.x >> 4, nt = blockIdx.x & 15;
  const int b = bh / 12, h = bh % 12;
  const int n0 = nt * 64;
  const int tid = threadIdx.x;
  const float s0 = g[3] + EPS_, s1 = g[4] + EPS_, s2 = g[5] + EPS_;
  const int r = tid >> 2, dc = tid & 3;             // row in tile, 16-elem d chunk
  const size_t mrow = (size_t)(b * 1024 + n0 + r) * 2304;
  // q part
  {
    const float4* src = (const float4*)(qkvf + mrow + h * 64 + dc * 16);
    *(int4*)&qo[((size_t)bh * 1024 + n0 + r) * 64 + dc * 16] =
        qpack16(src[0], src[1], src[2], src[3], s0);
  }
  // k part
  {
    const float4* src = (const float4*)(qkvf + mrow + 768 + h * 64 + dc * 16);
    *(int4*)&ko[((size_t)bh * 1024 + n0 + r) * 64 + dc * 16] =
        qpack16(src[0], src[1], src[2], src[3], s1);
  }
  // v part: stash transposed in LDS (f32), quantize+pack on the way out
  {
    const float4* src = (const float4*)(qkvf + mrow + 1536 + h * 64 + dc * 16);
    float4 v0 = src[0], v1 = src[1], v2 = src[2], v3 = src[3];
    vt[dc*16+ 0][r]=v0.x; vt[dc*16+ 1][r]=v0.y; vt[dc*16+ 2][r]=v0.z; vt[dc*16+ 3][r]=v0.w;
    vt[dc*16+ 4][r]=v1.x; vt[dc*16+ 5][r]=v1.y; vt[dc*16+ 6][r]=v1.z; vt[dc*16+ 7][r]=v1.w;
    vt[dc*16+ 8][r]=v2.x; vt[dc*16+ 9][r]=v2.y; vt[dc*16+10][r]=v2.z; vt[dc*16+11][r]=v2.w;
    vt[dc*16+12][r]=v3.x; vt[dc*16+13][r]=v3.y; vt[dc*16+14][r]=v3.z; vt[dc*16+15][r]=v3.w;
  }
  __syncthreads();
  {
    const int d = tid >> 2, nc = tid & 3;
    union { int4 v; int8_t c[16]; } pk;
    #pragma unroll
    for (int e = 0; e < 16; ++e) pk.c[e] = quant1(vt[d][nc * 16 + e], s2);
    *(int4*)&vT[((size_t)bh * 64 + d) * 1024 + n0 + nc * 16] = pk.v;
  }
}

// ---------------- attention pass 1 (native-i8 swapped QK^T, 64-row blocks, prefetch) --------
__global__ __launch_bounds__(256) void k_attn_stats_mfma(
    const int8_t* __restrict__ qi8, const int8_t* __restrict__ ki8,
    const float* __restrict__ g, float* __restrict__ rowmax, float* __restrict__ denomv,
    unsigned int* __restrict__ gminden) {
  __shared__ int8_t Ks[4][64][16];
  __shared__ float red[4];
  const int bh = blockIdx.x >> 4, rt = blockIdx.x & 15;
  const int tid = threadIdx.x, w = tid >> 6, lane = tid & 63;
  const int lrow = lane & 15, lslot = lane >> 4;
  const int8_t* qbase = qi8 + (size_t)bh * 65536;
  const int8_t* kbase = ki8 + (size_t)bh * 65536;
  const i32x4 qf = *(const i32x4*)(qbase + (size_t)(rt*64 + w*16 + lrow) * 64 + lslot * 16);
  const float qkScale = (g[3] + EPS_) * (g[4] + EPS_) * (1.0f / 16129.0f) * SCALE_;
  float m = -3.0e38f, den = 0.f;
  const int krow = tid & 63, kslot = tid >> 6;      // staging: 16B per thread
  int4 kraw = *(const int4*)(kbase + (size_t)krow * 64 + kslot * 16);
  for (int t = 0; t < 16; ++t) {
    __syncthreads();
    *(int4*)&Ks[kslot][krow][0] = kraw;
    if (t < 15)
      kraw = *(const int4*)(kbase + (size_t)(t + 1) * 4096 + (size_t)krow * 64 + kslot * 16);
    __syncthreads();
    i32x4 acc[4] = {};
    #pragma unroll
    for (int j = 0; j < 4; ++j) {
      i32x4 kf = *(const i32x4*)&Ks[lslot][j * 16 + lrow][0];
      acc[j] = __builtin_amdgcn_mfma_i32_16x16x64_i8(kf, qf, acc[j], 0, 0, 0);
    }
    float mnew = m;
    #pragma unroll
    for (int j = 0; j < 4; ++j)
      #pragma unroll
      for (int rr = 0; rr < 4; ++rr)
        mnew = fmaxf(mnew, (float)acc[j][rr] * qkScale);
    float d = den * __expf(m - mnew);
    #pragma unroll
    for (int j = 0; j < 4; ++j)
      #pragma unroll
      for (int rr = 0; rr < 4; ++rr)
        d += __expf((float)acc[j][rr] * qkScale - mnew);
    den = d; m = mnew;
  }
  // merge the 4 hi-lane k-partitions
  #pragma unroll
  for (int off = 16; off <= 32; off <<= 1) {
    float mo = __shfl_xor(m, off);
    float doo = __shfl_xor(den, off);
    float mg = fmaxf(m, mo);
    den = den * __expf(m - mg) + doo * __expf(mo - mg);
    m = mg;
  }
  if (lane < 16) {
    size_t rg = (size_t)bh * 1024 + rt * 64 + w * 16 + lane;
    rowmax[rg] = m;
    denomv[rg] = den;
  }
  // one atomic per block
  float bm = den;
  #pragma unroll
  for (int off = 1; off < 16; off <<= 1) bm = fminf(bm, __shfl_xor(bm, off));
  if (lane == 0) red[w] = bm;
  __syncthreads();
  if (tid == 0)
    atomicMin(gminden, __float_as_uint(fminf(fminf(red[0], red[1]), fminf(red[2], red[3]))));
}

// ---------------- attention pass 2 (i8 QK^T + bf16 PV, 64-row blocks, prefetch) -------------
__global__ __launch_bounds__(256) void k_attn_pv_mfma(
    const int8_t* __restrict__ qi8, const int8_t* __restrict__ ki8, const int8_t* __restrict__ vti8,
    const float* __restrict__ g, const unsigned int* __restrict__ gminden,
    const float* __restrict__ rowmax, const float* __restrict__ denomv,
    float* __restrict__ aof, float* __restrict__ gamax) {
  __shared__ int8_t Ks[4][64][16];
  __shared__ unsigned short Vs[64 * 64];
  __shared__ unsigned short Ps[64 * 64];
  __shared__ float red[4];
  const int bh = blockIdx.x >> 4, rt = blockIdx.x & 15;
  const int b = bh / 12, h = bh % 12;
  const int tid = threadIdx.x, w = tid >> 6, lane = tid & 63;
  const int lrow = lane & 15, lslot = lane >> 4, lko = lslot << 3;
  const int8_t* qbase = qi8 + (size_t)bh * 65536;
  const int8_t* kbase = ki8 + (size_t)bh * 65536;
  const int8_t* vbase = vti8 + (size_t)bh * 65536;
  const i32x4 qf = *(const i32x4*)(qbase + (size_t)(rt*64 + w*16 + lrow) * 64 + lslot * 16);
  const float qkScale = (g[3] + EPS_) * (g[4] + EPS_) * (1.0f / 16129.0f) * SCALE_;
  const float minden = __uint_as_float(*gminden);
  const float sa = 1.0f / minden + EPS_;
  const float invSa = 1.0f / sa;
  const float sv = g[5] + EPS_;
  const float pvScale = sa * sv * (1.0f / 32385.0f);   // /(255*127)
  const float rm  = rowmax[(size_t)bh * 1024 + rt * 64 + w * 16 + lrow];
  const float ivd = 1.0f / denomv[(size_t)bh * 1024 + rt * 64 + w * 16 + lrow];
  f32x4 accO[4] = {};
  const int krow = tid & 63, kslot = tid >> 6;      // K staging: raw int8, 16B/thread
  const int srow = tid >> 2, sc = tid & 3;          // V staging: expand to bf16, swizzled
  const int sx = (srow & 7) << 4;
  int4 kraw = *(const int4*)(kbase + (size_t)krow * 64 + kslot * 16);
  int4 vraw = *(const int4*)(vbase + (size_t)srow * 1024 + sc * 16);
  for (int t = 0; t < 16; ++t) {
    __syncthreads();
    *(int4*)&Ks[kslot][krow][0] = kraw;
    {
      int4 lo, hi;
      int bb = srow * 128 + sc * 32;
      expand16(vraw, lo, hi);
      *(int4*)((char*)Vs + ( bb       ^ sx)) = lo;
      *(int4*)((char*)Vs + ((bb + 16) ^ sx)) = hi;
    }
    if (t < 15) {
      kraw = *(const int4*)(kbase + (size_t)(t + 1) * 4096 + (size_t)krow * 64 + kslot * 16);
      vraw = *(const int4*)(vbase + (size_t)srow * 1024 + (t + 1) * 64 + sc * 16);
    }
    __syncthreads();
    i32x4 acc[4] = {};
    #pragma unroll
    for (int j = 0; j < 4; ++j) {
      i32x4 kf = *(const i32x4*)&Ks[lslot][j * 16 + lrow][0];
      acc[j] = __builtin_amdgcn_mfma_i32_16x16x64_i8(kf, qf, acc[j], 0, 0, 0);
    }
    // softmax -> unsigned 8-bit levels (exact bf16) -> Ps (in-lane)
    const int q = w * 16 + lrow;
    const int kb = lslot << 2;
    #pragma unroll
    for (int j = 0; j < 4; ++j) {
      float a0 = rintf(fminf(__expf((float)acc[j][0] * qkScale - rm) * ivd * invSa, 1.0f) * 255.0f);
      float a1 = rintf(fminf(__expf((float)acc[j][1] * qkScale - rm) * ivd * invSa, 1.0f) * 255.0f);
      float a2 = rintf(fminf(__expf((float)acc[j][2] * qkScale - rm) * ivd * invSa, 1.0f) * 255.0f);
      float a3 = rintf(fminf(__expf((float)acc[j][3] * qkScale - rm) * ivd * invSa, 1.0f) * 255.0f);
      uint2 pk;
      pk.x = (__float_as_uint(a0) >> 16) | ((__float_as_uint(a1) >> 16) << 16);
      pk.y = (__float_as_uint(a2) >> 16) | ((__float_as_uint(a3) >> 16) << 16);
      int byteoff = (q * 128 + (j * 16 + kb) * 2) ^ ((q & 7) << 4);
      *(uint2*)((char*)Ps + byteoff) = pk;
    }
    // O += P @ V  (bf16 MFMA; P in 0..255 exact bf16)
    #pragma unroll
    for (int ks = 0; ks < 2; ++ks) {
      bf16x8 pf = *(const bf16x8*)((const char*)Ps + ((q * 128 + (ks*32 + lko) * 2) ^ ((q & 7) << 4)));
      #pragma unroll
      for (int j = 0; j < 4; ++j) {
        int row = j * 16 + lrow;
        bf16x8 vf = *(const bf16x8*)((const char*)Vs + ((row * 128 + (ks*32 + lko) * 2) ^ ((row & 7) << 4)));
        accO[j] = __builtin_amdgcn_mfma_f32_16x16x32_bf16(pf, vf, accO[j], 0, 0, 0);
      }
    }
  }
  float amax = 0.f;
  #pragma unroll
  for (int j = 0; j < 4; ++j) {
    int d = j * 16 + lrow;
    #pragma unroll
    for (int rr = 0; rr < 4; ++rr) {
      int row = rt * 64 + w * 16 + (lane >> 4) * 4 + rr;
      float val = accO[j][rr] * pvScale;
      aof[((size_t)(b * 1024 + row)) * 768 + h * 64 + d] = val;
      amax = fmaxf(amax, fabsf(val));
    }
  }
  #pragma unroll
  for (int off = 1; off < 64; off <<= 1) amax = fmaxf(amax, __shfl_xor(amax, off));
  if (lane == 0) red[w] = amax;
  __syncthreads();
  if (tid == 0)
    atomicMax((unsigned int*)gamax, __float_as_uint(fmaxf(fmaxf(red[0], red[1]), fmaxf(red[2], red[3]))));
}

extern "C" void kernel_launch(void* const* d_in, const int* in_sizes, int n_in,
                              void* d_out, int out_size, void* d_ws, size_t ws_size,
                              hipStream_t stream) {
  const float* x      = (const float*)d_in[0];   // [8,1024,768]
  const float* qkv_w  = (const float*)d_in[1];   // [2304,768]
  const float* qkv_b  = (const float*)d_in[2];   // [2304]
  const float* proj_w = (const float*)d_in[3];   // [768,768]
  const float* proj_b = (const float*)d_in[4];   // [768]
  float* out = (float*)d_out;

  char* w = (char*)d_ws;
  float*          g      = (float*)(w + 0);                 // 8 stats
  float*          rowmax = (float*)(w + 256);               // 393216 B
  float*          denomv = (float*)(w + 393472);            // 393216 B
  int8_t*         qi8    = (int8_t*)(w + 786688);           // 6291456 B
  int8_t*         ki8    = (int8_t*)(w + 7078144);          // 6291456 B
  int8_t*         vT     = (int8_t*)(w + 13369600);         // 6291456 B
  int8_t*         pw8    = (int8_t*)(w + 19661056);         //  589824 B
  int8_t*         xq8    = (int8_t*)(w + 20840704);         // 6291456 B
  int8_t*         wq8    = (int8_t*)(w + 33423616);         // 1769472 B
  float*          qkvf   = (float*)(w + 36962560);          // 75497472 B f32 (dead after quant_heads)
  float*          aof    = (float*)(w + 36962560);          // 25165824 B (aliases dead qkvf)
  int8_t*         aob8   = (int8_t*)(w + 62128384);         // 6291456 B

  hipLaunchKernelGGL(k_init, dim3(1), dim3(64), 0, stream, g);

  hipLaunchKernelGGL(k_absmax_fused, dim3(528), dim3(256), 0, stream,
                     (const float4*)x, (const float4*)qkv_w, (const float4*)proj_w, g);

  hipLaunchKernelGGL(k_quant_fused, dim3(2112), dim3(256), 0, stream,
                     (const float4*)x, (const float4*)qkv_w, (const float4*)proj_w, g, xq8, wq8, pw8);

  // qkv = xq @ wq^T * (sx*sw/127^2) + b -> f32 [8192][2304]; per-part |max| -> g[3..5]
  hipLaunchKernelGGL(k_gemm8i, dim3(TC_ / 128, M_ / 128), dim3(256), 0, stream,
                     xq8, wq8, qkv_b, qkvf, M_, TC_, C_, &g[0], &g[1], &g[3], 768);

  hipLaunchKernelGGL(k_quant_heads, dim3(1536), dim3(256), 0, stream, qkvf, g, qi8, ki8, vT);

  hipLaunchKernelGGL(k_attn_stats_mfma, dim3(1536), dim3(256), 0, stream,
                     qi8, ki8, g, rowmax, denomv, (unsigned int*)&g[6]);
  hipLaunchKernelGGL(k_attn_pv_mfma, dim3(1536), dim3(256), 0, stream,
                     qi8, ki8, vT, g, (const unsigned int*)&g[6], rowmax, denomv, aof, &g[7]);

  hipLaunchKernelGGL(k_quant_i8, dim3(2048), dim3(256), 0, stream,
                     (const float4*)aof, 1572864u, &g[7], aob8);

  // out = aob8 @ pw8^T * (sao*spw/127^2) + proj_b -> d_out f32 [8192][768]
  hipLaunchKernelGGL(k_gemm8i, dim3(C_ / 128, M_ / 128), dim3(256), 0, stream,
                     aob8, pw8, proj_b, out, M_, C_, C_, &g[7], &g[2], (float*)nullptr, 1);

  (void)in_sizes; (void)n_in; (void)out_size; (void)ws_size;
}